// Round 5
// baseline (291.159 us; speedup 1.0000x reference)
//
#include <hip/hip_runtime.h>
#include <hip/hip_bf16.h>
#include <math.h>
#include <type_traits>

// Problem constants (fixed by setup_inputs)
#define BATCH 8
#define QLEN 900
#define HEADS 8
#define LEVELS 4
#define POINTS 4
#define NUM_KEYS 13294
#define BQ (BATCH * QLEN)          // 7200
#define MROWS_V (BATCH * NUM_KEYS) // 106352

__constant__ const int c_LH[4] = {100, 50, 25, 13};
__constant__ const int c_LW[4] = {100, 50, 25, 13};
__constant__ const int c_LS[4] = {0, 10000, 12500, 13125};

typedef __attribute__((ext_vector_type(8))) short bfrag;   // 8 bf16
typedef __attribute__((ext_vector_type(4))) float ffrag;   // 4 fp32 acc

static __device__ __forceinline__ unsigned short f2bf(float f) {
    __hip_bfloat16 h = __float2bfloat16(f);
    return *(unsigned short*)&h;
}
static __device__ __forceinline__ float bf2f(unsigned int u16) {
    unsigned int v = u16 << 16;
    float f;
    __builtin_memcpy(&f, &v, 4);
    return f;
}

// ---------------------------------------------------------------------------
// Merged prep: cast+transpose all three weight matrices to bf16 [n][k],
// concat off/attn biases. One launch.
// ---------------------------------------------------------------------------
__global__ __launch_bounds__(256)
void prep_kernel(const float* __restrict__ W_val, const float* __restrict__ W_off,
                 const float* __restrict__ W_attn, const float* __restrict__ W_out,
                 const float* __restrict__ b_off, const float* __restrict__ b_attn,
                 unsigned short* __restrict__ Wv, unsigned short* __restrict__ Woa,
                 unsigned short* __restrict__ Wo, float* __restrict__ boa) {
    const int id = blockIdx.x * 256 + threadIdx.x;
    if (id < 65536) {
        const int n = id >> 8, k = id & 255;
        Wv[id] = f2bf(W_val[k * 256 + n]);
    } else if (id < 131072) {
        const int t = id - 65536;
        const int n = t >> 8, k = t & 255;
        Woa[t] = f2bf(W_off[k * 256 + n]);
    } else if (id < 163840) {
        const int t = id - 131072;
        const int n = t >> 8, k = t & 255;       // n in 0..127
        Woa[65536 + t] = f2bf(W_attn[k * 128 + n]);
    } else if (id < 229376) {
        const int t = id - 163840;
        const int n = t >> 8, k = t & 255;
        Wo[t] = f2bf(W_out[k * 256 + n]);
    } else if (id < 229760) {
        const int t = id - 229376;
        boa[t] = (t < 256) ? b_off[t] : b_attn[t - 256];
    }
}

// ---------------------------------------------------------------------------
// Value projection v2: C[M,256] bf16 = bf16(A[M,256]) @ WT^T + bias.
// Grid (GX, 4). Block owns 64-col slice (n0), strides over 32-row M-tiles.
//  - B slice staged to LDS ONCE, then held in REGISTERS (2x8 bfrag = 64 VGPR)
//  - A tile = 32 rows x full K=256 in LDS -> NO K-loop, 2 barriers per M-tile
//  - register prefetch: next tile's global loads issued before compute,
//    in flight across compute+store (the restructured-pipeline path; the
//    old per-K barrier drained vmcnt(0) 4x per block -> 84us vs 26us floor)
// Wave w: row-tile rt = w&1 (16 rows), col-pair cp = w>>1 (32 cols).
// ---------------------------------------------------------------------------
#define VBM 32
#define VBN 64
#define VST 264   // shorts per row (132 dwords == 4 mod 32 banks)

__global__ __launch_bounds__(256, 3)
void vproj_mfma2(const float* __restrict__ A, const unsigned short* __restrict__ WT,
                 const float* __restrict__ bias, unsigned short* __restrict__ C,
                 int M) {
    __shared__ unsigned short Bs[VBN * VST];   // 33792 B
    __shared__ unsigned short As[VBM * VST];   // 16896 B
    const int tid = threadIdx.x;
    const int wave = tid >> 6, lane = tid & 63, ln = lane & 15, quad = lane >> 4;
    const int rt = wave & 1;
    const int cp = wave >> 1;
    const int n0 = blockIdx.y * VBN;

    // ---- stage B slice once: 64 n-rows x 256 k ----
    {
        const int r = tid >> 2;
        const int kc = (tid & 3) * 64;
        const uint4* src = (const uint4*)(WT + (size_t)(n0 + r) * 256 + kc);
        uint4* dst = (uint4*)&Bs[r * VST + kc];
#pragma unroll
        for (int i = 0; i < 8; ++i) dst[i] = src[i];
    }

    // A prefetch map: thread -> row = tid>>3 (0..31), 128B chunk c = tid&7
    const int arow = tid >> 3;
    const int ac = (tid & 7) * 32;   // floats

    const int NT = (M + VBM - 1) / VBM;
    int mt = blockIdx.x;

    float4 pf[8];
    {
        const int row = mt * VBM + arow;
        if (row < M) {
            const float4* p = (const float4*)(A + (size_t)row * 256 + ac);
#pragma unroll
            for (int i = 0; i < 8; ++i) pf[i] = p[i];
        } else {
#pragma unroll
            for (int i = 0; i < 8; ++i) pf[i] = make_float4(0.f, 0.f, 0.f, 0.f);
        }
    }
    __syncthreads();

    // ---- lift B fragments into registers: 2 coltiles x 8 kchunks ----
    bfrag bfr[2][8];
#pragma unroll
    for (int j = 0; j < 2; ++j)
#pragma unroll
        for (int kc = 0; kc < 8; ++kc)
            bfr[j][kc] = *(const bfrag*)&Bs[(cp * 32 + j * 16 + ln) * VST + kc * 32 + quad * 8];

    const float bb0 = bias[n0 + cp * 32 + ln];
    const float bb1 = bias[n0 + cp * 32 + 16 + ln];

    while (mt < NT) {
        // write prefetched tile regs -> As (cast fp32 -> bf16)
        {
            unsigned short u[32];
#pragma unroll
            for (int i = 0; i < 8; ++i) {
                u[i * 4 + 0] = f2bf(pf[i].x);
                u[i * 4 + 1] = f2bf(pf[i].y);
                u[i * 4 + 2] = f2bf(pf[i].z);
                u[i * 4 + 3] = f2bf(pf[i].w);
            }
            uint4* dst = (uint4*)&As[arow * VST + ac];
#pragma unroll
            for (int i = 0; i < 4; ++i) dst[i] = ((uint4*)u)[i];
        }
        const int cur = mt;
        mt += gridDim.x;
        __syncthreads();

        // issue next tile's prefetch (stays in flight through compute+store)
        if (mt < NT) {
            const int row = mt * VBM + arow;
            if (row < M) {
                const float4* p = (const float4*)(A + (size_t)row * 256 + ac);
#pragma unroll
                for (int i = 0; i < 8; ++i) pf[i] = p[i];
            } else {
#pragma unroll
                for (int i = 0; i < 8; ++i) pf[i] = make_float4(0.f, 0.f, 0.f, 0.f);
            }
        }

        // compute: 8 A-frag ds_reads, 16 MFMAs (B from regs)
        ffrag acc0 = (ffrag){0.f, 0.f, 0.f, 0.f};
        ffrag acc1 = (ffrag){0.f, 0.f, 0.f, 0.f};
#pragma unroll
        for (int kc = 0; kc < 8; ++kc) {
            bfrag af = *(const bfrag*)&As[(rt * 16 + ln) * VST + kc * 32 + quad * 8];
            acc0 = __builtin_amdgcn_mfma_f32_16x16x32_bf16(af, bfr[0][kc], acc0, 0, 0, 0);
            acc1 = __builtin_amdgcn_mfma_f32_16x16x32_bf16(af, bfr[1][kc], acc1, 0, 0, 0);
        }

        // store 16x32 wave tile
        const int rbase = cur * VBM + rt * 16 + quad * 4;
#pragma unroll
        for (int r = 0; r < 4; ++r) {
            const int row = rbase + r;
            if (row < M) {
                C[(size_t)row * 256 + n0 + cp * 32 + ln] = f2bf(acc0[r] + bb0);
                C[(size_t)row * 256 + n0 + cp * 32 + 16 + ln] = f2bf(acc1[r] + bb1);
            }
        }
        __syncthreads();   // readers done before next As overwrite
    }
}

// ---------------------------------------------------------------------------
// bf16-MFMA GEMM (small projections): C[M,N] = bf16(A[M,256]) @ WT^T + bias.
// ---------------------------------------------------------------------------
#define GST 72

template <typename AT, typename CT>
__global__ __launch_bounds__(256)
void gemm_mfma(const AT* __restrict__ A, const unsigned short* __restrict__ WT,
               const float* __restrict__ bias, CT* __restrict__ C,
               int M, int ldc) {
    __shared__ unsigned short As[64 * GST];
    __shared__ unsigned short Bs[128 * GST];
    const int tid = threadIdx.x;
    const int wave = tid >> 6;
    const int lane = tid & 63;
    const int ln = lane & 15;
    const int quad = lane >> 4;
    const int m0 = blockIdx.x * 64;
    const int n0 = blockIdx.y * 128;

    ffrag acc[8];
#pragma unroll
    for (int j = 0; j < 8; ++j) acc[j] = (ffrag){0.f, 0.f, 0.f, 0.f};

    const int ar = tid >> 2;
    const int akc = (tid & 3) * 16;
    const int brow = tid >> 1;
    const int bkc = (tid & 1) * 32;
    const bool a_ok = (m0 + ar) < M;
    const AT* a_src = A + (size_t)(m0 + ar) * 256 + akc;
    const unsigned short* b_src = WT + (size_t)(n0 + brow) * 256 + bkc;

    for (int k0 = 0; k0 < 256; k0 += 64) {
        unsigned short* adst = &As[ar * GST + akc];
        if constexpr (std::is_same<AT, float>::value) {
            float4 f0, f1, f2, f3;
            if (a_ok) {
                const float4* p = (const float4*)(a_src + k0);
                f0 = p[0]; f1 = p[1]; f2 = p[2]; f3 = p[3];
            } else {
                f0 = make_float4(0.f, 0.f, 0.f, 0.f);
                f1 = f0; f2 = f0; f3 = f0;
            }
            float v[16] = {f0.x, f0.y, f0.z, f0.w, f1.x, f1.y, f1.z, f1.w,
                           f2.x, f2.y, f2.z, f2.w, f3.x, f3.y, f3.z, f3.w};
            unsigned short u[16];
#pragma unroll
            for (int i = 0; i < 16; ++i) u[i] = f2bf(v[i]);
            ((uint4*)adst)[0] = ((uint4*)u)[0];
            ((uint4*)adst)[1] = ((uint4*)u)[1];
        } else {
            uint4 u0, u1;
            if (a_ok) {
                const uint4* p = (const uint4*)(a_src + k0);
                u0 = p[0]; u1 = p[1];
            } else {
                u0 = make_uint4(0, 0, 0, 0);
                u1 = u0;
            }
            ((uint4*)adst)[0] = u0;
            ((uint4*)adst)[1] = u1;
        }
        {
            const uint4* src = (const uint4*)(b_src + k0);
            uint4* dst = (uint4*)&Bs[brow * GST + bkc];
#pragma unroll
            for (int i = 0; i < 4; ++i) dst[i] = src[i];
        }
        __syncthreads();

#pragma unroll
        for (int ks = 0; ks < 2; ++ks) {
            const int koff = ks * 32 + quad * 8;
            bfrag af = *(const bfrag*)&As[(wave * 16 + ln) * GST + koff];
#pragma unroll
            for (int j = 0; j < 8; ++j) {
                bfrag bf = *(const bfrag*)&Bs[(j * 16 + ln) * GST + koff];
                acc[j] = __builtin_amdgcn_mfma_f32_16x16x32_bf16(af, bf, acc[j], 0, 0, 0);
            }
        }
        __syncthreads();
    }

#pragma unroll
    for (int j = 0; j < 8; ++j) {
        const int col = n0 + j * 16 + ln;
        const float bb = bias[col];
#pragma unroll
        for (int r = 0; r < 4; ++r) {
            const int row = m0 + wave * 16 + quad * 4 + r;
            if (row < M) {
                const float v = acc[j][r] + bb;
                if constexpr (std::is_same<CT, unsigned short>::value) {
                    C[(size_t)row * ldc + col] = f2bf(v);
                } else {
                    C[(size_t)row * ldc + col] = v;
                }
            }
        }
    }
}

// ---------------------------------------------------------------------------
// Fused softmax + locations + bilinear sampling over bf16 values.
// (unchanged from round 4: launch_bounds(256,4) + point-loop unroll 2)
// ---------------------------------------------------------------------------
__global__ __launch_bounds__(256, 4)
void msda_sample_kernel(const float* __restrict__ offattn,  // [BQ][384]
                        const float* __restrict__ rp,
                        const unsigned short* __restrict__ vb,  // (b,key,256) bf16
                        unsigned short* __restrict__ outb) {    // (bq,256) bf16
    const int bq0 = blockIdx.x * 8;
    const int tid = threadIdx.x;

    __shared__ float s_w[8][128];
    __shared__ float s_x[8][128];
    __shared__ float s_y[8][128];

#pragma unroll
    for (int i = 0; i < 4; ++i) {
        const int e = i * 256 + tid;
        const int q = e >> 7, t = e & 127;
        s_w[q][t] = offattn[(size_t)(bq0 + q) * 384 + 256 + t];
    }
    __syncthreads();

    if (tid < 64) {
        const int q = tid >> 3, h = tid & 7;
        float m = -1e30f;
#pragma unroll
        for (int i = 0; i < 16; ++i) m = fmaxf(m, s_w[q][h * 16 + i]);
        float e[16];
        float s = 0.f;
#pragma unroll
        for (int i = 0; i < 16; ++i) {
            e[i] = expf(s_w[q][h * 16 + i] - m);
            s += e[i];
        }
        const float inv = 1.f / s;
#pragma unroll
        for (int i = 0; i < 16; ++i) s_w[q][h * 16 + i] = e[i] * inv;
    }

#pragma unroll
    for (int i = 0; i < 4; ++i) {
        const int e = i * 256 + tid;
        const int q = e >> 7, t = e & 127;
        const int h = t >> 4, l = (t >> 2) & 3, p = t & 3;
        const int bq = bq0 + q;
        const float2 off = *(const float2*)(offattn + (size_t)bq * 384 + h * 32 + l * 8 + p * 2);
        const float Wl = (float)c_LW[l];
        const float Hl = (float)c_LH[l];
        const float rx = rp[((size_t)bq * 4 + l) * 2 + 0];
        const float ry = rp[((size_t)bq * 4 + l) * 2 + 1];
        s_x[q][t] = (rx + off.x / Wl) * Wl - 0.5f;
        s_y[q][t] = (ry + off.y / Hl) * Hl - 0.5f;
    }
    __syncthreads();

    const int q = tid >> 5;
    const int s = tid & 31;
    const int h = s >> 2;
    const int dp = s & 3;
    const int bq = bq0 + q;
    const int b = bq / QLEN;
    const unsigned short* vbase = vb + (size_t)b * NUM_KEYS * 256 + h * 32 + dp * 8;

    float acc[8];
#pragma unroll
    for (int d = 0; d < 8; ++d) acc[d] = 0.f;

#pragma unroll
    for (int l = 0; l < LEVELS; ++l) {
        const int Hl = c_LH[l];
        const int Wl = c_LW[l];
        const int s0 = c_LS[l];
#pragma unroll 2
        for (int p = 0; p < POINTS; ++p) {
            const int t2 = h * 16 + l * 4 + p;
            const float x = s_x[q][t2];
            const float y = s_y[q][t2];
            const float w = s_w[q][t2];
            const float x0f = floorf(x);
            const float y0f = floorf(y);
            const float wx = x - x0f;
            const float wy = y - y0f;
            const int x0 = (int)x0f;
            const int y0 = (int)y0f;
            const float mx0 = ((unsigned)x0 < (unsigned)Wl) ? 1.f : 0.f;
            const float mx1 = ((unsigned)(x0 + 1) < (unsigned)Wl) ? 1.f : 0.f;
            const float my0 = ((unsigned)y0 < (unsigned)Hl) ? 1.f : 0.f;
            const float my1 = ((unsigned)(y0 + 1) < (unsigned)Hl) ? 1.f : 0.f;
            const int xc0 = min(max(x0, 0), Wl - 1);
            const int xc1 = min(max(x0 + 1, 0), Wl - 1);
            const int yc0 = min(max(y0, 0), Hl - 1);
            const int yc1 = min(max(y0 + 1, 0), Hl - 1);
            const float a00 = w * (1.f - wx) * (1.f - wy) * mx0 * my0;
            const float a01 = w * wx * (1.f - wy) * mx1 * my0;
            const float a10 = w * (1.f - wx) * wy * mx0 * my1;
            const float a11 = w * wx * wy * mx1 * my1;
            const size_t k00 = (size_t)(s0 + yc0 * Wl + xc0) * 256;
            const size_t k01 = (size_t)(s0 + yc0 * Wl + xc1) * 256;
            const size_t k10 = (size_t)(s0 + yc1 * Wl + xc0) * 256;
            const size_t k11 = (size_t)(s0 + yc1 * Wl + xc1) * 256;
            const uint4 r00 = *(const uint4*)(vbase + k00);
            const uint4 r01 = *(const uint4*)(vbase + k01);
            const uint4 r10 = *(const uint4*)(vbase + k10);
            const uint4 r11 = *(const uint4*)(vbase + k11);
            const unsigned int w00[4] = {r00.x, r00.y, r00.z, r00.w};
            const unsigned int w01[4] = {r01.x, r01.y, r01.z, r01.w};
            const unsigned int w10[4] = {r10.x, r10.y, r10.z, r10.w};
            const unsigned int w11[4] = {r11.x, r11.y, r11.z, r11.w};
#pragma unroll
            for (int i = 0; i < 4; ++i) {
                const float v00l = bf2f(w00[i] & 0xffffu), v00h = bf2f(w00[i] >> 16);
                const float v01l = bf2f(w01[i] & 0xffffu), v01h = bf2f(w01[i] >> 16);
                const float v10l = bf2f(w10[i] & 0xffffu), v10h = bf2f(w10[i] >> 16);
                const float v11l = bf2f(w11[i] & 0xffffu), v11h = bf2f(w11[i] >> 16);
                acc[i * 2 + 0] = fmaf(a00, v00l, fmaf(a01, v01l, fmaf(a10, v10l, fmaf(a11, v11l, acc[i * 2 + 0]))));
                acc[i * 2 + 1] = fmaf(a00, v00h, fmaf(a01, v01h, fmaf(a10, v10h, fmaf(a11, v11h, acc[i * 2 + 1]))));
            }
        }
    }

    unsigned short o[8];
#pragma unroll
    for (int d = 0; d < 8; ++d) o[d] = f2bf(acc[d]);
    *(uint4*)(outb + (size_t)bq * 256 + h * 32 + dp * 8) = *(uint4*)o;
}

// ---------------------------------------------------------------------------
extern "C" void kernel_launch(void* const* d_in, const int* in_sizes, int n_in,
                              void* d_out, int out_size, void* d_ws, size_t ws_size,
                              hipStream_t stream) {
    const float* query  = (const float*)d_in[0];
    const float* rp     = (const float*)d_in[1];
    const float* value  = (const float*)d_in[2];
    const float* W_off  = (const float*)d_in[5];
    const float* b_off  = (const float*)d_in[6];
    const float* W_attn = (const float*)d_in[7];
    const float* b_attn = (const float*)d_in[8];
    const float* W_val  = (const float*)d_in[9];
    const float* b_val  = (const float*)d_in[10];
    const float* W_out  = (const float*)d_in[11];
    const float* b_out  = (const float*)d_in[12];
    float* out = (float*)d_out;

    // workspace layout
    char* w = (char*)d_ws;
    unsigned short* ws_vb = (unsigned short*)w;                 // MROWS_V*256 bf16
    w += (size_t)MROWS_V * 256 * 2;
    float* ws_offattn = (float*)w;                              // BQ*384 f32
    w += (size_t)BQ * 384 * 4;
    unsigned short* ws_msda = (unsigned short*)w;               // BQ*256 bf16
    w += (size_t)BQ * 256 * 2;
    unsigned short* ws_Wv = (unsigned short*)w;  w += 256 * 256 * 2;   // [n][k]
    unsigned short* ws_Woa = (unsigned short*)w; w += 384 * 256 * 2;   // [n][k]
    unsigned short* ws_Wo = (unsigned short*)w;  w += 256 * 256 * 2;   // [n][k]
    float* ws_boa = (float*)w;                                   // 384 f32

    // 0. merged weight prep (bf16, transposed) + bias concat
    prep_kernel<<<898, 256, 0, stream>>>(W_val, W_off, W_attn, W_out,
                                         b_off, b_attn, ws_Wv, ws_Woa, ws_Wo, ws_boa);

    // 1. value projection -> bf16 (M=106352, N=256), pipelined M-loop
    {
        dim3 grid(384, 4);
        vproj_mfma2<<<grid, 256, 0, stream>>>(value, ws_Wv, b_val, ws_vb, MROWS_V);
    }
    // 2. fused offset+attn projection -> fp32 (M=7200, N=384)
    {
        dim3 grid((BQ + 63) / 64, 3);
        gemm_mfma<float, float><<<grid, 256, 0, stream>>>(
            query, ws_Woa, ws_boa, ws_offattn, BQ, 384);
    }
    // 3. softmax + locations + bilinear sampling (8 queries/block)
    msda_sample_kernel<<<BQ / 8, 256, 0, stream>>>(ws_offattn, rp, ws_vb, ws_msda);

    // 4. output projection -> d_out fp32 (M=7200, N=256)
    {
        dim3 grid((BQ + 63) / 64, 2);
        gemm_mfma<unsigned short, float><<<grid, 256, 0, stream>>>(
            ws_msda, ws_Wo, b_out, out, BQ, 256);
    }
}